// Round 10
// baseline (200.199 us; speedup 1.0000x reference)
//
#include <hip/hip_runtime.h>
#include <hip/hip_bf16.h>
#include <math.h>

// Problem constants
#define BB 2
#define NN 2048
#define DIM 512
#define NH 8
#define HD 64
#define SCALE 0.125f

typedef __bf16 bf16x8 __attribute__((ext_vector_type(8)));
typedef __bf16 bf16x4 __attribute__((ext_vector_type(4)));
typedef float floatx4 __attribute__((ext_vector_type(4)));
typedef float floatx16 __attribute__((ext_vector_type(16)));

static inline __device__ floatx4 mfma16(bf16x8 a, bf16x8 b, floatx4 c) {
    return __builtin_amdgcn_mfma_f32_16x16x32_bf16(a, b, c, 0, 0, 0);
}
static inline __device__ floatx16 mfma32(bf16x8 a, bf16x8 b, floatx16 c) {
    return __builtin_amdgcn_mfma_f32_32x32x16_bf16(a, b, c, 0, 0, 0);
}

static inline __device__ bf16x8 cvt8(float4 a, float4 b) {
    bf16x8 r;
    r[0] = (__bf16)a.x; r[1] = (__bf16)a.y; r[2] = (__bf16)a.z; r[3] = (__bf16)a.w;
    r[4] = (__bf16)b.x; r[5] = (__bf16)b.y; r[6] = (__bf16)b.z; r[7] = (__bf16)b.w;
    return r;
}

static inline __device__ float bf2f(unsigned short u) {
    return __uint_as_float(((unsigned)u) << 16);
}

// async global->LDS, 16 B per lane; lds base must be wave-uniform
static inline __device__ void dma16(const void* g, void* l) {
    __builtin_amdgcn_global_load_lds(
        (const __attribute__((address_space(1))) unsigned int*)g,
        (__attribute__((address_space(3))) unsigned int*)l,
        16, 0, 0);
}

// ---------------------------------------------------------------------------
// Kernel 1: prep — adj row stats + xcast + two weight transpose-casts.
//   [0,4096):      adj softmax stats -> rmax, rsum
//   [4096,5120):   x fp32 -> bf16
//   [5120,5888):   w_qkv -> wqkvT bf16
//   [5888,6144):   w_out -> woutT bf16
// ---------------------------------------------------------------------------
__global__ __launch_bounds__(256) void prep(const float* __restrict__ adj,
                                            float* __restrict__ rmax,
                                            float* __restrict__ rsum,
                                            const float* __restrict__ x,
                                            __bf16* __restrict__ xb,
                                            const float* __restrict__ w_qkv,
                                            __bf16* __restrict__ wqkvT,
                                            const float* __restrict__ w_out,
                                            __bf16* __restrict__ woutT) {
    __shared__ __align__(16) float smem[32][33];
    const int blk = blockIdx.x;
    const int t = threadIdx.x;

    if (blk < 4096) {
        const float* a = adj + (size_t)blk * NN;
        int w = t >> 6, lane = t & 63;
        float4 va = *(const float4*)(a + 4 * t);
        float4 vb = *(const float4*)(a + 1024 + 4 * t);
        float v[8] = {va.x, va.y, va.z, va.w, vb.x, vb.y, vb.z, vb.w};
        float mx = -INFINITY;
#pragma unroll
        for (int c = 0; c < 8; ++c) mx = fmaxf(mx, v[c]);
#pragma unroll
        for (int s = 1; s < 64; s <<= 1) mx = fmaxf(mx, __shfl_xor(mx, s));
        float* red = &smem[0][0];
        if (lane == 0) red[w] = mx;
        __syncthreads();
        mx = fmaxf(fmaxf(red[0], red[1]), fmaxf(red[2], red[3]));
        float sm = 0.f;
#pragma unroll
        for (int c = 0; c < 8; ++c) sm += __expf(v[c] - mx);
#pragma unroll
        for (int s = 1; s < 64; s <<= 1) sm += __shfl_xor(sm, s);
        if (lane == 0) red[4 + w] = sm;
        __syncthreads();
        if (t == 0) {
            rmax[blk] = mx;
            rsum[blk] = (red[4] + red[5]) + (red[6] + red[7]);
        }
    } else if (blk < 5120) {
        int g = (blk - 4096) * 256 + t;
        float4 f0 = ((const float4*)x)[2 * (size_t)g];
        float4 f1 = ((const float4*)x)[2 * (size_t)g + 1];
        *(bf16x8*)(xb + 8 * (size_t)g) = cvt8(f0, f1);
    } else {
        const float* w; __bf16* wT; int K, N, bx, by;
        if (blk < 5888) {
            int idx = blk - 5120;
            w = w_qkv; wT = wqkvT; K = 512; N = 1536;
            bx = idx % 48; by = idx / 48;
        } else {
            int idx = blk - 5888;
            w = w_out; wT = woutT; K = 512; N = 512;
            bx = idx % 16; by = idx / 16;
        }
        int n0 = bx * 32, k0 = by * 32;
        int c = t & 31, r = t >> 5;
#pragma unroll
        for (int p = 0; p < 4; ++p)
            smem[r + p * 8][c] = w[(size_t)(k0 + r + p * 8) * N + n0 + c];
        __syncthreads();
#pragma unroll
        for (int p = 0; p < 4; ++p)
            wT[(size_t)(n0 + r + p * 8) * K + k0 + c] = (__bf16)smem[c][r + p * 8];
    }
}

// ---------------------------------------------------------------------------
// Kernel 1b: maskT[b][j][i] = softmax(adj)[b][i][j], 64x64 tiles.
// grid = BB * 32 * 32 = 2048 blocks.
// ---------------------------------------------------------------------------
__global__ __launch_bounds__(256) void mask_t(const float* __restrict__ adj,
                                              const float* __restrict__ rmax,
                                              const float* __restrict__ rsum,
                                              __bf16* __restrict__ maskT) {
    __shared__ __bf16 sm[64][72];
    const int idx = blockIdx.x;
    const int b = idx >> 10;
    const int it = (idx >> 5) & 31, jt = idx & 31;
    const int t = threadIdx.x;
    const int r = t >> 2, cc = (t & 3) * 16;
    const int i = it * 64 + r;

    const float* arow = adj + ((size_t)b * NN + i) * NN + jt * 64 + cc;
    float mx = rmax[b * NN + i];
    float inv = 1.0f / rsum[b * NN + i];
    float4 f0 = *(const float4*)arow;
    float4 f1 = *(const float4*)(arow + 4);
    float4 f2 = *(const float4*)(arow + 8);
    float4 f3 = *(const float4*)(arow + 12);
    float vv[16] = {f0.x, f0.y, f0.z, f0.w, f1.x, f1.y, f1.z, f1.w,
                    f2.x, f2.y, f2.z, f2.w, f3.x, f3.y, f3.z, f3.w};
    bf16x8 p0, p1;
#pragma unroll
    for (int e = 0; e < 8; ++e) {
        p0[e] = (__bf16)(__expf(vv[e] - mx) * inv);
        p1[e] = (__bf16)(__expf(vv[8 + e] - mx) * inv);
    }
    *(bf16x8*)(&sm[r][cc]) = p0;
    *(bf16x8*)(&sm[r][cc + 8]) = p1;
    __syncthreads();
    // transposed write: row j = r, cols i
    bf16x8 o1, o2;
#pragma unroll
    for (int e = 0; e < 8; ++e) {
        o1[e] = sm[cc + e][r];
        o2[e] = sm[cc + 8 + e][r];
    }
    __bf16* dst = maskT + ((size_t)b * NN + jt * 64 + r) * NN + it * 64 + cc;
    *(bf16x8*)dst = o1;
    *(bf16x8*)(dst + 8) = o2;
}

// ---------------------------------------------------------------------------
// Kernel 2: qkv = xb @ w_qkv via MFMA + DMA staging. (unchanged)
// ---------------------------------------------------------------------------
__global__ __launch_bounds__(256) void qkv_mfma(const __bf16* __restrict__ xb,
                                                const __bf16* __restrict__ wT,
                                                __bf16* __restrict__ q,
                                                __bf16* __restrict__ kk,
                                                __bf16* __restrict__ vT) {
    __shared__ __bf16 As[128 * 64];   // 16 KB
    __shared__ __bf16 Bs[64 * 64];    // 8 KB
    const int t = threadIdx.x;
    const int lane = t & 63, w = t >> 6;
    const int n16 = lane & 15, quad = lane >> 4;
    const int wm = w >> 1, wn = w & 1;
    const int m0 = blockIdx.y * 128, n0 = blockIdx.x * 64;

    const int srow = t >> 3;
    const int schunk = (t & 7) ^ ((t >> 3) & 7);
    const int woff = w * 1024;
    const int rchunk = (n16 & 7);

    floatx4 acc[4][2];
#pragma unroll
    for (int mt = 0; mt < 4; ++mt)
#pragma unroll
        for (int nt = 0; nt < 2; ++nt) acc[mt][nt] = (floatx4){0.f, 0.f, 0.f, 0.f};

    for (int k0 = 0; k0 < 512; k0 += 64) {
        __syncthreads();
#pragma unroll
        for (int d = 0; d < 4; ++d)
            dma16(xb + (size_t)(m0 + d * 32 + srow) * 512 + k0 + schunk * 8,
                  (char*)As + d * 4096 + woff);
#pragma unroll
        for (int d = 0; d < 2; ++d)
            dma16(wT + (size_t)(n0 + d * 32 + srow) * 512 + k0 + schunk * 8,
                  (char*)Bs + d * 4096 + woff);
        __syncthreads();
#pragma unroll
        for (int kh = 0; kh < 2; ++kh) {
            const int ch = (kh * 4 + quad) ^ rchunk;
            bf16x8 af[4], bf[2];
#pragma unroll
            for (int mt = 0; mt < 4; ++mt)
                af[mt] = *(const bf16x8*)(As + (wm * 64 + mt * 16 + n16) * 64 + ch * 8);
#pragma unroll
            for (int nt = 0; nt < 2; ++nt)
                bf[nt] = *(const bf16x8*)(Bs + (wn * 32 + nt * 16 + n16) * 64 + ch * 8);
#pragma unroll
            for (int mt = 0; mt < 4; ++mt)
#pragma unroll
                for (int nt = 0; nt < 2; ++nt)
                    acc[mt][nt] = mfma16(af[mt], bf[nt], acc[mt][nt]);
        }
    }

#pragma unroll
    for (int mt = 0; mt < 4; ++mt)
#pragma unroll
        for (int nt = 0; nt < 2; ++nt)
#pragma unroll
            for (int r = 0; r < 4; ++r) {
                int m = m0 + wm * 64 + mt * 16 + quad * 4 + r;
                int n = n0 + wn * 32 + nt * 16 + n16;
                int b = m >> 11, i = m & 2047;
                int sg = n >> 9, cc = n & 511;
                int h = cc >> 6, d = cc & 63;
                size_t bh = (size_t)(b * NH + h);
                float fv = acc[mt][nt][r];
                if (sg == 0)      q[(bh * NN + i) * HD + d] = (__bf16)(fv * SCALE);
                else if (sg == 1) kk[(bh * NN + i) * HD + d] = (__bf16)fv;
                else              vT[(bh * HD + d) * NN + i] = (__bf16)fv;
            }
}

// ---------------------------------------------------------------------------
// Kernel 3: flash attention, 32x32 MFMA, split-j x4, poly-exp, DMA staging,
// coalesced maskT reads, XOR-swizzled Ps.
// Block = (b, h, 128 q-rows, jsplit), 4 waves x 32 i-rows; 8 j-iters of 64.
// ---------------------------------------------------------------------------
__global__ __launch_bounds__(256, 4) void flash_attn(const __bf16* __restrict__ qb,
                                                     const __bf16* __restrict__ kb,
                                                     const __bf16* __restrict__ vTb,
                                                     const __bf16* __restrict__ maskT,
                                                     __bf16* __restrict__ Opart,
                                                     float* __restrict__ lpart) {
    __shared__ __bf16 Ks[64 * 64];    // 8 KB, rows j-local, XOR swizzle
    __shared__ __bf16 Vs[64 * 64];    // 8 KB, rows d, XOR swizzle
    __shared__ __bf16 Ps[128 * 64];   // 16 KB, rows i-local, XOR swizzle

    const int t = threadIdx.x;
    const int lane = t & 63;
    const int w = t >> 6;            // wave -> 32-row i-strip
    const int l32 = lane & 31;
    const int half = lane >> 5;

    const int blk = blockIdx.x;
    const int split = blk & 3;
    const int it = (blk >> 2) & 15;
    const int h = (blk >> 6) & 7;
    const int b = blk >> 9;
    const int i0 = it * 128;
    const int bh = b * NH + h;
    const int iw = i0 + w * 32 + l32;

    // Q B-frags: B[k=d][n=i]
    bf16x8 qf[4];
    {
        const __bf16* qrow = qb + ((size_t)bh * NN + iw) * HD;
#pragma unroll
        for (int kc = 0; kc < 4; ++kc)
            qf[kc] = *(const bf16x8*)(qrow + kc * 16 + half * 8);
    }

    floatx16 O0 = {}, O1 = {};
    float lp = 0.f;

    const int drow = t >> 3;
    const int dchunk = (t & 7) ^ ((t >> 3) & 7);
    const int woff = w * 1024;
    const int rs = l32 & 7;          // read-side XOR key (row&7)
    const int R = w * 32 + l32;      // Ps row (wave-local)

    const __bf16* kg = kb + (size_t)bh * NN * HD;
    const __bf16* vg = vTb + (size_t)bh * HD * NN;
    const __bf16* mT = maskT + (size_t)b * NN * NN + iw;   // + j*NN per element

    int j0 = split * (NN / 4);
    for (int iter = 0; iter < (NN / 4) / 64; ++iter, j0 += 64) {
        __syncthreads();             // prior-iter LDS reads complete
#pragma unroll
        for (int d = 0; d < 2; ++d) {
            dma16(kg + (size_t)(j0 + d * 32 + drow) * HD + dchunk * 8,
                  (char*)Ks + d * 4096 + woff);
            dma16(vg + (size_t)(d * 32 + drow) * NN + j0 + dchunk * 8,
                  (char*)Vs + d * 4096 + woff);
        }
        __syncthreads();             // drains vmcnt (dma) too

        // coalesced mask loads (lane dim = i): tile 0 rows j0+jl
        float mv0[16];
#pragma unroll
        for (int g = 0; g < 4; ++g)
#pragma unroll
            for (int rr = 0; rr < 4; ++rr) {
                int jl = g * 8 + half * 4 + rr;
                mv0[g * 4 + rr] =
                    bf2f(*(const unsigned short*)(mT + (size_t)(j0 + jl) * NN));
            }

        // S^T = K * Q^T, tile 0 (j-rows 0..31)
        floatx16 S0 = {};
#pragma unroll
        for (int kc = 0; kc < 4; ++kc) {
            const int cs = ((kc * 2 + half) ^ rs) * 8;
            S0 = mfma32(*(const bf16x8*)(Ks + l32 * 64 + cs), qf[kc], S0);
        }

        float mv1[16];
#pragma unroll
        for (int g = 0; g < 4; ++g)
#pragma unroll
            for (int rr = 0; rr < 4; ++rr) {
                int jl = g * 8 + half * 4 + rr;
                mv1[g * 4 + rr] =
                    bf2f(*(const unsigned short*)(mT + (size_t)(j0 + 32 + jl) * NN));
            }

        floatx16 S1 = {};
#pragma unroll
        for (int kc = 0; kc < 4; ++kc) {
            const int cs = ((kc * 2 + half) ^ rs) * 8;
            S1 = mfma32(*(const bf16x8*)(Ks + (32 + l32) * 64 + cs), qf[kc], S1);
        }

        // p = 1 + x + x^2/2 (|x| <= ~5e-3); write P to wave-local swizzled LDS
#pragma unroll
        for (int g = 0; g < 4; ++g) {
            bf16x4 pk0, pk1;
#pragma unroll
            for (int rr = 0; rr < 4; ++rr) {
                float x0 = S0[g * 4 + rr] * mv0[g * 4 + rr];
                float x1 = S1[g * 4 + rr] * mv1[g * 4 + rr];
                float p0 = fmaf(x0, fmaf(0.5f, x0, 1.0f), 1.0f);
                float p1 = fmaf(x1, fmaf(0.5f, x1, 1.0f), 1.0f);
                lp += p0 + p1;
                pk0[rr] = (__bf16)p0;
                pk1[rr] = (__bf16)p1;
            }
            *(bf16x4*)(Ps + R * 64 + ((g ^ rs) * 8) + half * 4) = pk0;
            *(bf16x4*)(Ps + R * 64 + (((g + 4) ^ rs) * 8) + half * 4) = pk1;
        }

        // PV: O[i][d] += P[i][j] V[j][d]
#pragma unroll
        for (int kc = 0; kc < 4; ++kc) {
            const int cs = ((kc * 2 + half) ^ rs) * 8;
            bf16x8 pf  = *(const bf16x8*)(Ps + R * 64 + cs);
            bf16x8 vf0 = *(const bf16x8*)(Vs + l32 * 64 + cs);
            bf16x8 vf1 = *(const bf16x8*)(Vs + (32 + l32) * 64 + cs);
            O0 = mfma32(pf, vf0, O0);
            O1 = mfma32(pf, vf1, O1);
        }
    }

    // epilogue
    lp += __shfl_xor(lp, 32);
    const size_t sb = (size_t)(split * BB * NH + bh);
    if (half == 0)
        lpart[sb * NN + iw] = lp;
#pragma unroll
    for (int reg = 0; reg < 16; ++reg) {
        int i = i0 + w * 32 + (reg & 3) + 8 * (reg >> 2) + 4 * half;
        Opart[(sb * NN + i) * HD + l32] = (__bf16)O0[reg];
        Opart[(sb * NN + i) * HD + 32 + l32] = (__bf16)O1[reg];
    }
}

// ---------------------------------------------------------------------------
// Kernel 4: combine 4 splits -> ohb [b, n, h*d] bf16
// ---------------------------------------------------------------------------
__global__ __launch_bounds__(256) void combine(const __bf16* __restrict__ Opart,
                                               const float* __restrict__ lpart,
                                               __bf16* __restrict__ ohb) {
    int g = blockIdx.x * 256 + threadIdx.x;      // 262144 threads
    int d0 = (g & 7) * 8;
    int n = (g >> 3) & 2047;
    int bh = g >> 14;                            // 0..15
    int b = bh >> 3, h = bh & 7;
    float o[8] = {};
    float l = 0.f;
#pragma unroll
    for (int s = 0; s < 4; ++s) {
        size_t sb = (size_t)(s * BB * NH + bh);
        bf16x8 ov = *(const bf16x8*)(Opart + (sb * NN + n) * HD + d0);
#pragma unroll
        for (int e = 0; e < 8; ++e) o[e] += (float)ov[e];
        l += lpart[sb * NN + n];
    }
    float inv = 1.0f / l;
    bf16x8 r;
#pragma unroll
    for (int e = 0; e < 8; ++e) r[e] = (__bf16)(o[e] * inv);
    *(bf16x8*)(ohb + ((size_t)b * NN + n) * (NH * HD) + h * HD + d0) = r;
}

// ---------------------------------------------------------------------------
// Kernel 5: out = ohb @ w_out + b_out via MFMA + DMA staging.
// ---------------------------------------------------------------------------
__global__ __launch_bounds__(256) void out_mfma(const __bf16* __restrict__ A,
                                                const __bf16* __restrict__ wT,
                                                const float* __restrict__ bias,
                                                float* __restrict__ out) {
    __shared__ __bf16 As[64 * 64];    // 8 KB
    __shared__ __bf16 Bs[64 * 64];    // 8 KB
    const int t = threadIdx.x;
    const int lane = t & 63, w = t >> 6;
    const int n16 = lane & 15, quad = lane >> 4;
    const int wm = w >> 1, wn = w & 1;
    const int m0 = blockIdx.y * 64, n0 = blockIdx.x * 64;

    const int srow = t >> 3;
    const int schunk = (t & 7) ^ ((t >> 3) & 7);
    const int woff = w * 1024;
    const int rchunk = (n16 & 7);

    floatx4 acc[2][2];
#pragma unroll
    for (int mt = 0; mt < 2; ++mt)
#pragma unroll
        for (int nt = 0; nt < 2; ++nt) acc[mt][nt] = (floatx4){0.f, 0.f, 0.f, 0.f};

    for (int k0 = 0; k0 < 512; k0 += 64) {
        __syncthreads();
#pragma unroll
        for (int d = 0; d < 2; ++d) {
            dma16(A + (size_t)(m0 + d * 32 + srow) * 512 + k0 + schunk * 8,
                  (char*)As + d * 4096 + woff);
            dma16(wT + (size_t)(n0 + d * 32 + srow) * 512 + k0 + schunk * 8,
                  (char*)Bs + d * 4096 + woff);
        }
        __syncthreads();
#pragma unroll
        for (int kh = 0; kh < 2; ++kh) {
            const int ch = (kh * 4 + quad) ^ rchunk;
            bf16x8 af[2], bf[2];
#pragma unroll
            for (int mt = 0; mt < 2; ++mt)
                af[mt] = *(const bf16x8*)(As + (wm * 32 + mt * 16 + n16) * 64 + ch * 8);
#pragma unroll
            for (int nt = 0; nt < 2; ++nt)
                bf[nt] = *(const bf16x8*)(Bs + (wn * 32 + nt * 16 + n16) * 64 + ch * 8);
#pragma unroll
            for (int mt = 0; mt < 2; ++mt)
#pragma unroll
                for (int nt = 0; nt < 2; ++nt)
                    acc[mt][nt] = mfma16(af[mt], bf[nt], acc[mt][nt]);
        }
    }

#pragma unroll
    for (int mt = 0; mt < 2; ++mt)
#pragma unroll
        for (int nt = 0; nt < 2; ++nt)
#pragma unroll
            for (int r = 0; r < 4; ++r) {
                int m = m0 + wm * 32 + mt * 16 + quad * 4 + r;
                int n = n0 + wn * 32 + nt * 16 + n16;
                out[(size_t)m * 512 + n] = acc[mt][nt][r] + bias[n];
            }
}

extern "C" void kernel_launch(void* const* d_in, const int* in_sizes, int n_in,
                              void* d_out, int out_size, void* d_ws, size_t ws_size,
                              hipStream_t stream) {
    const float* x     = (const float*)d_in[0];
    const float* adj   = (const float*)d_in[1];
    const float* w_qkv = (const float*)d_in[2];
    const float* w_out = (const float*)d_in[3];
    const float* b_out = (const float*)d_in[4];
    float* out = (float*)d_out;
    char* wsb = (char*)d_ws;

    // workspace byte layout (<= 48.8 MiB, same footprint as proven rounds)
    __bf16* wqkvT = (__bf16*)(wsb + 0);                  // 1.5 MiB
    __bf16* woutT = (__bf16*)(wsb + (3u << 19));         // 0.5 MiB
    __bf16* q     = (__bf16*)(wsb + (2u << 20));         // 4 MiB
    __bf16* ohb   = (__bf16*)(wsb + (2u << 20));         // aliases q (q dead at combine)
    float*  rmax  = (float*) (wsb + (2u << 20));         // 16 KiB, inside q (dead before qkv writes q)
    float*  rsum  = (float*) (wsb + (2u << 20) + 16384); // 16 KiB
    __bf16* k     = (__bf16*)(wsb + (6u << 20));         // 4 MiB
    __bf16* vT    = (__bf16*)(wsb + (10u << 20));        // 4 MiB
    __bf16* maskT = (__bf16*)(wsb + (14u << 20));        // 16 MiB
    __bf16* Opart = (__bf16*)(wsb + (30u << 20));        // 16 MiB (4 splits)
    __bf16* xb    = (__bf16*)(wsb + (30u << 20));        // aliases Opart (dead after qkv)
    float*  lpart = (float*) (wsb + (46u << 20));        // 512 KiB

    prep<<<6144, 256, 0, stream>>>(adj, rmax, rsum, x, xb, w_qkv, wqkvT, w_out, woutT);
    mask_t<<<2048, 256, 0, stream>>>(adj, rmax, rsum, maskT);
    qkv_mfma<<<dim3(1536 / 64, 4096 / 128), 256, 0, stream>>>(xb, wqkvT, q, k, vT);
    flash_attn<<<BB * NH * 16 * 4, 256, 0, stream>>>(q, k, vT, maskT, Opart, lpart);
    combine<<<1024, 256, 0, stream>>>(Opart, lpart, ohb);
    out_mfma<<<dim3(512 / 64, 4096 / 64), 256, 0, stream>>>(ohb, woutT, b_out, out);
}

// Round 11
// 150.664 us; speedup vs baseline: 1.3288x; 1.3288x over previous
//
#include <hip/hip_runtime.h>
#include <hip/hip_bf16.h>
#include <math.h>

// Problem constants
#define BB 2
#define NN 2048
#define DIM 512
#define NH 8
#define HD 64
#define SCALE 0.125f

typedef __bf16 bf16x8 __attribute__((ext_vector_type(8)));
typedef __bf16 bf16x4 __attribute__((ext_vector_type(4)));
typedef float floatx4 __attribute__((ext_vector_type(4)));
typedef float floatx16 __attribute__((ext_vector_type(16)));
typedef unsigned long long u64;

static inline __device__ floatx4 mfma16(bf16x8 a, bf16x8 b, floatx4 c) {
    return __builtin_amdgcn_mfma_f32_16x16x32_bf16(a, b, c, 0, 0, 0);
}
static inline __device__ floatx16 mfma32(bf16x8 a, bf16x8 b, floatx16 c) {
    return __builtin_amdgcn_mfma_f32_32x32x16_bf16(a, b, c, 0, 0, 0);
}

static inline __device__ bf16x8 cvt8(float4 a, float4 b) {
    bf16x8 r;
    r[0] = (__bf16)a.x; r[1] = (__bf16)a.y; r[2] = (__bf16)a.z; r[3] = (__bf16)a.w;
    r[4] = (__bf16)b.x; r[5] = (__bf16)b.y; r[6] = (__bf16)b.z; r[7] = (__bf16)b.w;
    return r;
}

union pk_u64 { bf16x4 v; u64 u; };
union frag_u64 { bf16x8 v; u64 u[2]; };

// async global->LDS, 16 B per lane; lds base must be wave-uniform
static inline __device__ void dma16(const void* g, void* l) {
    __builtin_amdgcn_global_load_lds(
        (const __attribute__((address_space(1))) unsigned int*)g,
        (__attribute__((address_space(3))) unsigned int*)l,
        16, 0, 0);
}

// ---------------------------------------------------------------------------
// Kernel 1: prep — fused adj_softmax(->bf16 mask) + xcast + weight transposes.
// ---------------------------------------------------------------------------
__global__ __launch_bounds__(256) void prep(const float* __restrict__ adj,
                                            __bf16* __restrict__ mask,
                                            const float* __restrict__ x,
                                            __bf16* __restrict__ xb,
                                            const float* __restrict__ w_qkv,
                                            __bf16* __restrict__ wqkvT,
                                            const float* __restrict__ w_out,
                                            __bf16* __restrict__ woutT) {
    __shared__ __align__(16) float smem[32][33];
    const int blk = blockIdx.x;
    const int t = threadIdx.x;

    if (blk < 4096) {
        const float* a = adj + (size_t)blk * NN;
        __bf16* m = mask + (size_t)blk * NN;
        int w = t >> 6, lane = t & 63;
        float4 va = *(const float4*)(a + 4 * t);
        float4 vb = *(const float4*)(a + 1024 + 4 * t);
        float v[8] = {va.x, va.y, va.z, va.w, vb.x, vb.y, vb.z, vb.w};
        float mx = -INFINITY;
#pragma unroll
        for (int c = 0; c < 8; ++c) mx = fmaxf(mx, v[c]);
#pragma unroll
        for (int s = 1; s < 64; s <<= 1) mx = fmaxf(mx, __shfl_xor(mx, s));
        float* red = &smem[0][0];
        if (lane == 0) red[w] = mx;
        __syncthreads();
        mx = fmaxf(fmaxf(red[0], red[1]), fmaxf(red[2], red[3]));
        float sm = 0.f;
        float e[8];
#pragma unroll
        for (int c = 0; c < 8; ++c) { e[c] = __expf(v[c] - mx); sm += e[c]; }
#pragma unroll
        for (int s = 1; s < 64; s <<= 1) sm += __shfl_xor(sm, s);
        if (lane == 0) red[4 + w] = sm;
        __syncthreads();
        float inv = 1.0f / ((red[4] + red[5]) + (red[6] + red[7]));
        bf16x4 o0, o1;
#pragma unroll
        for (int c = 0; c < 4; ++c) {
            o0[c] = (__bf16)(e[c] * inv);
            o1[c] = (__bf16)(e[c + 4] * inv);
        }
        *(bf16x4*)(m + 4 * t) = o0;
        *(bf16x4*)(m + 1024 + 4 * t) = o1;
    } else if (blk < 5120) {
        int g = (blk - 4096) * 256 + t;
        float4 f0 = ((const float4*)x)[2 * (size_t)g];
        float4 f1 = ((const float4*)x)[2 * (size_t)g + 1];
        *(bf16x8*)(xb + 8 * (size_t)g) = cvt8(f0, f1);
    } else {
        const float* w; __bf16* wT; int K, N, bx, by;
        if (blk < 5888) {
            int idx = blk - 5120;
            w = w_qkv; wT = wqkvT; K = 512; N = 1536;
            bx = idx % 48; by = idx / 48;
        } else {
            int idx = blk - 5888;
            w = w_out; wT = woutT; K = 512; N = 512;
            bx = idx % 16; by = idx / 16;
        }
        int n0 = bx * 32, k0 = by * 32;
        int c = t & 31, r = t >> 5;
#pragma unroll
        for (int p = 0; p < 4; ++p)
            smem[r + p * 8][c] = w[(size_t)(k0 + r + p * 8) * N + n0 + c];
        __syncthreads();
#pragma unroll
        for (int p = 0; p < 4; ++p)
            wT[(size_t)(n0 + r + p * 8) * K + k0 + c] = (__bf16)smem[c][r + p * 8];
    }
}

// ---------------------------------------------------------------------------
// Kernel 2: qkv = xb @ w_qkv via MFMA + DMA staging. (unchanged)
// ---------------------------------------------------------------------------
__global__ __launch_bounds__(256) void qkv_mfma(const __bf16* __restrict__ xb,
                                                const __bf16* __restrict__ wT,
                                                __bf16* __restrict__ q,
                                                __bf16* __restrict__ kk,
                                                __bf16* __restrict__ vT) {
    __shared__ __bf16 As[128 * 64];   // 16 KB
    __shared__ __bf16 Bs[64 * 64];    // 8 KB
    const int t = threadIdx.x;
    const int lane = t & 63, w = t >> 6;
    const int n16 = lane & 15, quad = lane >> 4;
    const int wm = w >> 1, wn = w & 1;
    const int m0 = blockIdx.y * 128, n0 = blockIdx.x * 64;

    const int srow = t >> 3;
    const int schunk = (t & 7) ^ ((t >> 3) & 7);
    const int woff = w * 1024;
    const int rchunk = (n16 & 7);

    floatx4 acc[4][2];
#pragma unroll
    for (int mt = 0; mt < 4; ++mt)
#pragma unroll
        for (int nt = 0; nt < 2; ++nt) acc[mt][nt] = (floatx4){0.f, 0.f, 0.f, 0.f};

    for (int k0 = 0; k0 < 512; k0 += 64) {
        __syncthreads();
#pragma unroll
        for (int d = 0; d < 4; ++d)
            dma16(xb + (size_t)(m0 + d * 32 + srow) * 512 + k0 + schunk * 8,
                  (char*)As + d * 4096 + woff);
#pragma unroll
        for (int d = 0; d < 2; ++d)
            dma16(wT + (size_t)(n0 + d * 32 + srow) * 512 + k0 + schunk * 8,
                  (char*)Bs + d * 4096 + woff);
        __syncthreads();
#pragma unroll
        for (int kh = 0; kh < 2; ++kh) {
            const int ch = (kh * 4 + quad) ^ rchunk;
            bf16x8 af[4], bf[2];
#pragma unroll
            for (int mt = 0; mt < 4; ++mt)
                af[mt] = *(const bf16x8*)(As + (wm * 64 + mt * 16 + n16) * 64 + ch * 8);
#pragma unroll
            for (int nt = 0; nt < 2; ++nt)
                bf[nt] = *(const bf16x8*)(Bs + (wn * 32 + nt * 16 + n16) * 64 + ch * 8);
#pragma unroll
            for (int mt = 0; mt < 4; ++mt)
#pragma unroll
                for (int nt = 0; nt < 2; ++nt)
                    acc[mt][nt] = mfma16(af[mt], bf[nt], acc[mt][nt]);
        }
    }

#pragma unroll
    for (int mt = 0; mt < 4; ++mt)
#pragma unroll
        for (int nt = 0; nt < 2; ++nt)
#pragma unroll
            for (int r = 0; r < 4; ++r) {
                int m = m0 + wm * 64 + mt * 16 + quad * 4 + r;
                int n = n0 + wn * 32 + nt * 16 + n16;
                int b = m >> 11, i = m & 2047;
                int sg = n >> 9, cc = n & 511;
                int h = cc >> 6, d = cc & 63;
                size_t bh = (size_t)(b * NH + h);
                float fv = acc[mt][nt][r];
                if (sg == 0)      q[(bh * NN + i) * HD + d] = (__bf16)(fv * SCALE);
                else if (sg == 1) kk[(bh * NN + i) * HD + d] = (__bf16)fv;
                else              vT[(bh * HD + d) * NN + i] = (__bf16)fv;
            }
}

// ---------------------------------------------------------------------------
// Kernel 3: flash attention, 32x32 MFMA, split-j x4, poly-exp.
// K/V/M all staged via dma16 into XOR-swizzled LDS; P exchanged in-register
// via shfl_xor(32) (no Ps LDS). LDS = 32 KB -> 5 blocks/CU.
// Block = (b, h, 128 q-rows, jsplit), 4 waves x 32 i-rows; 8 j-iters of 64.
// ---------------------------------------------------------------------------
__global__ __launch_bounds__(256, 4) void flash_attn(const __bf16* __restrict__ qb,
                                                     const __bf16* __restrict__ kb,
                                                     const __bf16* __restrict__ vTb,
                                                     const __bf16* __restrict__ maskb,
                                                     __bf16* __restrict__ Opart,
                                                     float* __restrict__ lpart) {
    __shared__ __bf16 Ks[64 * 64];    // 8 KB, rows j-local, XOR swizzle
    __shared__ __bf16 Vs[64 * 64];    // 8 KB, rows d, XOR swizzle
    __shared__ __bf16 Ms[128 * 64];   // 16 KB, rows i-local, XOR swizzle

    const int t = threadIdx.x;
    const int lane = t & 63;
    const int w = t >> 6;            // wave -> 32-row i-strip
    const int l32 = lane & 31;
    const int half = lane >> 5;

    const int blk = blockIdx.x;
    const int split = blk & 3;
    const int it = (blk >> 2) & 15;
    const int h = (blk >> 6) & 7;
    const int b = blk >> 9;
    const int i0 = it * 128;
    const int bh = b * NH + h;
    const int il = w * 32 + l32;     // i-local in [0,128)
    const int iw = i0 + il;

    // Q B-frags: B[k=d][n=i]
    bf16x8 qf[4];
    {
        const __bf16* qrow = qb + ((size_t)bh * NN + iw) * HD;
#pragma unroll
        for (int kc = 0; kc < 4; ++kc)
            qf[kc] = *(const bf16x8*)(qrow + kc * 16 + half * 8);
    }

    floatx16 O0 = {}, O1 = {};       // D[m=i][n=d]: col d = l32 / 32+l32
    float lp = 0.f;

    const int drow = t >> 3;
    const int dchunk = (t & 7) ^ ((t >> 3) & 7);
    const int woff = w * 1024;
    const int rs = l32 & 7;          // read-side XOR key (row&7)

    const __bf16* kg = kb + (size_t)bh * NN * HD;
    const __bf16* vg = vTb + (size_t)bh * HD * NN;
    const __bf16* mg = maskb + ((size_t)b * NN + i0) * NN;   // block's mask tile rows

    int j0 = split * (NN / 4);
    for (int iter = 0; iter < (NN / 4) / 64; ++iter, j0 += 64) {
        __syncthreads();             // prior-iter LDS reads complete
#pragma unroll
        for (int d = 0; d < 2; ++d) {
            dma16(kg + (size_t)(j0 + d * 32 + drow) * HD + dchunk * 8,
                  (char*)Ks + d * 4096 + woff);
            dma16(vg + (size_t)(d * 32 + drow) * NN + j0 + dchunk * 8,
                  (char*)Vs + d * 4096 + woff);
        }
#pragma unroll
        for (int d = 0; d < 4; ++d)
            dma16(mg + (size_t)(d * 32 + drow) * NN + j0 + dchunk * 8,
                  (char*)Ms + d * 4096 + woff);
        __syncthreads();             // drains vmcnt (dma) too

        // S^T = K * Q^T: rows j = 8G+4*half+rr, col i = l32
        floatx16 S0 = {}, S1 = {};
#pragma unroll
        for (int kc = 0; kc < 4; ++kc) {
            const int cs = ((kc * 2 + half) ^ rs) * 8;
            S0 = mfma32(*(const bf16x8*)(Ks + l32 * 64 + cs), qf[kc], S0);
            S1 = mfma32(*(const bf16x8*)(Ks + (32 + l32) * 64 + cs), qf[kc], S1);
        }

        // p = 1 + x + x^2/2, x = mask*s (|x| <= ~5e-3)
        pk_u64 pk[8];
#pragma unroll
        for (int G = 0; G < 8; ++G) {
            bf16x4 mv = *(const bf16x4*)(Ms + il * 64 + ((G ^ rs) * 8) + half * 4);
#pragma unroll
            for (int rr = 0; rr < 4; ++rr) {
                float s = (G < 4) ? S0[(G & 3) * 4 + rr] : S1[(G & 3) * 4 + rr];
                float x = s * (float)mv[rr];
                float p = fmaf(x, fmaf(0.5f, x, 1.0f), 1.0f);
                lp += p;
                pk[G].v[rr] = (__bf16)p;
            }
        }

        // PV: O[i][d] += P[i][j] V[j][d].
        // A-frag k=j=16kc+8*half+e: e0-3 from half0's pk[2kc+h], e4-7 from half1's.
#pragma unroll
        for (int kc = 0; kc < 4; ++kc) {
            u64 pa = pk[2 * kc].u, pb = pk[2 * kc + 1].u;
            u64 send = half ? pa : pb;
            u64 recv = __shfl_xor(send, 32);
            frag_u64 af;
            af.u[0] = half ? recv : pa;
            af.u[1] = half ? pb : recv;
            const int cs = ((kc * 2 + half) ^ rs) * 8;
            O0 = mfma32(af.v, *(const bf16x8*)(Vs + l32 * 64 + cs), O0);
            O1 = mfma32(af.v, *(const bf16x8*)(Vs + (32 + l32) * 64 + cs), O1);
        }
    }

    // epilogue (d = l32 coalesced, as R8)
    lp += __shfl_xor(lp, 32);
    const size_t sb = (size_t)(split * BB * NH + bh);
    if (half == 0)
        lpart[sb * NN + iw] = lp;
#pragma unroll
    for (int reg = 0; reg < 16; ++reg) {
        int i = i0 + w * 32 + (reg & 3) + 8 * (reg >> 2) + 4 * half;
        Opart[(sb * NN + i) * HD + l32] = (__bf16)O0[reg];
        Opart[(sb * NN + i) * HD + 32 + l32] = (__bf16)O1[reg];
    }
}

// ---------------------------------------------------------------------------
// Kernel 4: combine 4 splits -> ohb [b, n, h*d] bf16
// ---------------------------------------------------------------------------
__global__ __launch_bounds__(256) void combine(const __bf16* __restrict__ Opart,
                                               const float* __restrict__ lpart,
                                               __bf16* __restrict__ ohb) {
    int g = blockIdx.x * 256 + threadIdx.x;      // 262144 threads
    int d0 = (g & 7) * 8;
    int n = (g >> 3) & 2047;
    int bh = g >> 14;                            // 0..15
    int b = bh >> 3, h = bh & 7;
    float o[8] = {};
    float l = 0.f;
#pragma unroll
    for (int s = 0; s < 4; ++s) {
        size_t sb = (size_t)(s * BB * NH + bh);
        bf16x8 ov = *(const bf16x8*)(Opart + (sb * NN + n) * HD + d0);
#pragma unroll
        for (int e = 0; e < 8; ++e) o[e] += (float)ov[e];
        l += lpart[sb * NN + n];
    }
    float inv = 1.0f / l;
    bf16x8 r;
#pragma unroll
    for (int e = 0; e < 8; ++e) r[e] = (__bf16)(o[e] * inv);
    *(bf16x8*)(ohb + ((size_t)b * NN + n) * (NH * HD) + h * HD + d0) = r;
}

// ---------------------------------------------------------------------------
// Kernel 5: out = ohb @ w_out + b_out via MFMA + DMA staging.
// ---------------------------------------------------------------------------
__global__ __launch_bounds__(256) void out_mfma(const __bf16* __restrict__ A,
                                                const __bf16* __restrict__ wT,
                                                const float* __restrict__ bias,
                                                float* __restrict__ out) {
    __shared__ __bf16 As[64 * 64];    // 8 KB
    __shared__ __bf16 Bs[64 * 64];    // 8 KB
    const int t = threadIdx.x;
    const int lane = t & 63, w = t >> 6;
    const int n16 = lane & 15, quad = lane >> 4;
    const int wm = w >> 1, wn = w & 1;
    const int m0 = blockIdx.y * 64, n0 = blockIdx.x * 64;

    const int srow = t >> 3;
    const int schunk = (t & 7) ^ ((t >> 3) & 7);
    const int woff = w * 1024;
    const int rchunk = (n16 & 7);

    floatx4 acc[2][2];
#pragma unroll
    for (int mt = 0; mt < 2; ++mt)
#pragma unroll
        for (int nt = 0; nt < 2; ++nt) acc[mt][nt] = (floatx4){0.f, 0.f, 0.f, 0.f};

    for (int k0 = 0; k0 < 512; k0 += 64) {
        __syncthreads();
#pragma unroll
        for (int d = 0; d < 2; ++d) {
            dma16(A + (size_t)(m0 + d * 32 + srow) * 512 + k0 + schunk * 8,
                  (char*)As + d * 4096 + woff);
            dma16(wT + (size_t)(n0 + d * 32 + srow) * 512 + k0 + schunk * 8,
                  (char*)Bs + d * 4096 + woff);
        }
        __syncthreads();
#pragma unroll
        for (int kh = 0; kh < 2; ++kh) {
            const int ch = (kh * 4 + quad) ^ rchunk;
            bf16x8 af[2], bf[2];
#pragma unroll
            for (int mt = 0; mt < 2; ++mt)
                af[mt] = *(const bf16x8*)(As + (wm * 32 + mt * 16 + n16) * 64 + ch * 8);
#pragma unroll
            for (int nt = 0; nt < 2; ++nt)
                bf[nt] = *(const bf16x8*)(Bs + (wn * 32 + nt * 16 + n16) * 64 + ch * 8);
#pragma unroll
            for (int mt = 0; mt < 2; ++mt)
#pragma unroll
                for (int nt = 0; nt < 2; ++nt)
                    acc[mt][nt] = mfma16(af[mt], bf[nt], acc[mt][nt]);
        }
    }

#pragma unroll
    for (int mt = 0; mt < 2; ++mt)
#pragma unroll
        for (int nt = 0; nt < 2; ++nt)
#pragma unroll
            for (int r = 0; r < 4; ++r) {
                int m = m0 + wm * 32 + mt * 16 + quad * 4 + r;
                int n = n0 + wn * 32 + nt * 16 + n16;
                out[(size_t)m * 512 + n] = acc[mt][nt][r] + bias[n];
            }
}

extern "C" void kernel_launch(void* const* d_in, const int* in_sizes, int n_in,
                              void* d_out, int out_size, void* d_ws, size_t ws_size,
                              hipStream_t stream) {
    const float* x     = (const float*)d_in[0];
    const float* adj   = (const float*)d_in[1];
    const float* w_qkv = (const float*)d_in[2];
    const float* w_out = (const float*)d_in[3];
    const float* b_out = (const float*)d_in[4];
    float* out = (float*)d_out;
    char* wsb = (char*)d_ws;

    // workspace byte layout (46.5 MiB)
    __bf16* wqkvT = (__bf16*)(wsb + 0);                  // 1.5 MiB
    __bf16* woutT = (__bf16*)(wsb + (3u << 19));         // 0.5 MiB
    __bf16* q     = (__bf16*)(wsb + (2u << 20));         // 4 MiB
    __bf16* ohb   = (__bf16*)(wsb + (2u << 20));         // aliases q (q dead at combine)
    __bf16* k     = (__bf16*)(wsb + (6u << 20));         // 4 MiB
    __bf16* vT    = (__bf16*)(wsb + (10u << 20));        // 4 MiB
    __bf16* mask  = (__bf16*)(wsb + (14u << 20));        // 16 MiB
    __bf16* Opart = (__bf16*)(wsb + (30u << 20));        // 16 MiB (4 splits)
    __bf16* xb    = (__bf16*)(wsb + (30u << 20));        // aliases Opart (dead after qkv)
    float*  lpart = (float*) (wsb + (46u << 20));        // 512 KiB

    prep<<<6144, 256, 0, stream>>>(adj, mask, x, xb, w_qkv, wqkvT, w_out, woutT);
    qkv_mfma<<<dim3(1536 / 64, 4096 / 128), 256, 0, stream>>>(xb, wqkvT, q, k, vT);
    flash_attn<<<BB * NH * 16 * 4, 256, 0, stream>>>(q, k, vT, mask, Opart, lpart);
    combine<<<1024, 256, 0, stream>>>(Opart, lpart, ohb);
    out_mfma<<<dim3(512 / 64, 4096 / 64), 256, 0, stream>>>(ohb, woutT, b_out, out);
}

// Round 12
// 147.155 us; speedup vs baseline: 1.3605x; 1.0238x over previous
//
#include <hip/hip_runtime.h>
#include <hip/hip_bf16.h>
#include <math.h>

// Problem constants
#define BB 2
#define NN 2048
#define DIM 512
#define NH 8
#define HD 64
#define SCALE 0.125f

typedef __bf16 bf16x8 __attribute__((ext_vector_type(8)));
typedef __bf16 bf16x4 __attribute__((ext_vector_type(4)));
typedef float floatx4 __attribute__((ext_vector_type(4)));
typedef float floatx16 __attribute__((ext_vector_type(16)));
typedef unsigned long long u64;

static inline __device__ floatx4 mfma16(bf16x8 a, bf16x8 b, floatx4 c) {
    return __builtin_amdgcn_mfma_f32_16x16x32_bf16(a, b, c, 0, 0, 0);
}
static inline __device__ floatx16 mfma32(bf16x8 a, bf16x8 b, floatx16 c) {
    return __builtin_amdgcn_mfma_f32_32x32x16_bf16(a, b, c, 0, 0, 0);
}

static inline __device__ bf16x8 cvt8(float4 a, float4 b) {
    bf16x8 r;
    r[0] = (__bf16)a.x; r[1] = (__bf16)a.y; r[2] = (__bf16)a.z; r[3] = (__bf16)a.w;
    r[4] = (__bf16)b.x; r[5] = (__bf16)b.y; r[6] = (__bf16)b.z; r[7] = (__bf16)b.w;
    return r;
}

union pk_u64 { bf16x4 v; u64 u; };
union frag_u64 { bf16x8 v; u64 u[2]; };

// async global->LDS, 16 B per lane; lds base must be wave-uniform
static inline __device__ void dma16(const void* g, void* l) {
    __builtin_amdgcn_global_load_lds(
        (const __attribute__((address_space(1))) unsigned int*)g,
        (__attribute__((address_space(3))) unsigned int*)l,
        16, 0, 0);
}

// ---------------------------------------------------------------------------
// Kernel 1: prep — fused adj_softmax(->bf16 mask) + xcast + weight transposes.
// ---------------------------------------------------------------------------
__global__ __launch_bounds__(256) void prep(const float* __restrict__ adj,
                                            __bf16* __restrict__ mask,
                                            const float* __restrict__ x,
                                            __bf16* __restrict__ xb,
                                            const float* __restrict__ w_qkv,
                                            __bf16* __restrict__ wqkvT,
                                            const float* __restrict__ w_out,
                                            __bf16* __restrict__ woutT) {
    __shared__ __align__(16) float smem[32][33];
    const int blk = blockIdx.x;
    const int t = threadIdx.x;

    if (blk < 4096) {
        const float* a = adj + (size_t)blk * NN;
        __bf16* m = mask + (size_t)blk * NN;
        int w = t >> 6, lane = t & 63;
        float4 va = *(const float4*)(a + 4 * t);
        float4 vb = *(const float4*)(a + 1024 + 4 * t);
        float v[8] = {va.x, va.y, va.z, va.w, vb.x, vb.y, vb.z, vb.w};
        float mx = -INFINITY;
#pragma unroll
        for (int c = 0; c < 8; ++c) mx = fmaxf(mx, v[c]);
#pragma unroll
        for (int s = 1; s < 64; s <<= 1) mx = fmaxf(mx, __shfl_xor(mx, s));
        float* red = &smem[0][0];
        if (lane == 0) red[w] = mx;
        __syncthreads();
        mx = fmaxf(fmaxf(red[0], red[1]), fmaxf(red[2], red[3]));
        float sm = 0.f;
        float e[8];
#pragma unroll
        for (int c = 0; c < 8; ++c) { e[c] = __expf(v[c] - mx); sm += e[c]; }
#pragma unroll
        for (int s = 1; s < 64; s <<= 1) sm += __shfl_xor(sm, s);
        if (lane == 0) red[4 + w] = sm;
        __syncthreads();
        float inv = 1.0f / ((red[4] + red[5]) + (red[6] + red[7]));
        bf16x4 o0, o1;
#pragma unroll
        for (int c = 0; c < 4; ++c) {
            o0[c] = (__bf16)(e[c] * inv);
            o1[c] = (__bf16)(e[c + 4] * inv);
        }
        *(bf16x4*)(m + 4 * t) = o0;
        *(bf16x4*)(m + 1024 + 4 * t) = o1;
    } else if (blk < 5120) {
        int g = (blk - 4096) * 256 + t;
        float4 f0 = ((const float4*)x)[2 * (size_t)g];
        float4 f1 = ((const float4*)x)[2 * (size_t)g + 1];
        *(bf16x8*)(xb + 8 * (size_t)g) = cvt8(f0, f1);
    } else {
        const float* w; __bf16* wT; int K, N, bx, by;
        if (blk < 5888) {
            int idx = blk - 5120;
            w = w_qkv; wT = wqkvT; K = 512; N = 1536;
            bx = idx % 48; by = idx / 48;
        } else {
            int idx = blk - 5888;
            w = w_out; wT = woutT; K = 512; N = 512;
            bx = idx % 16; by = idx / 16;
        }
        int n0 = bx * 32, k0 = by * 32;
        int c = t & 31, r = t >> 5;
#pragma unroll
        for (int p = 0; p < 4; ++p)
            smem[r + p * 8][c] = w[(size_t)(k0 + r + p * 8) * N + n0 + c];
        __syncthreads();
#pragma unroll
        for (int p = 0; p < 4; ++p)
            wT[(size_t)(n0 + r + p * 8) * K + k0 + c] = (__bf16)smem[c][r + p * 8];
    }
}

// ---------------------------------------------------------------------------
// Kernel 2: qkv = xb @ w_qkv via MFMA + DMA staging.
// For v-segment blocks (n0 >= 1024) the MFMA operands are swapped so the
// C-layout is transposed in-register: lane col = i (contiguous) -> coalesced
// vT stores (4 lines/store inst instead of 64).
// ---------------------------------------------------------------------------
__global__ __launch_bounds__(256) void qkv_mfma(const __bf16* __restrict__ xb,
                                                const __bf16* __restrict__ wT,
                                                __bf16* __restrict__ q,
                                                __bf16* __restrict__ kk,
                                                __bf16* __restrict__ vT) {
    __shared__ __bf16 As[128 * 64];   // 16 KB
    __shared__ __bf16 Bs[64 * 64];    // 8 KB
    const int t = threadIdx.x;
    const int lane = t & 63, w = t >> 6;
    const int n16 = lane & 15, quad = lane >> 4;
    const int wm = w >> 1, wn = w & 1;
    const int m0 = blockIdx.y * 128, n0 = blockIdx.x * 64;
    const bool isv = (n0 >= 1024);    // block-uniform

    const int srow = t >> 3;
    const int schunk = (t & 7) ^ ((t >> 3) & 7);
    const int woff = w * 1024;
    const int rchunk = (n16 & 7);

    floatx4 acc[4][2];
#pragma unroll
    for (int mt = 0; mt < 4; ++mt)
#pragma unroll
        for (int nt = 0; nt < 2; ++nt) acc[mt][nt] = (floatx4){0.f, 0.f, 0.f, 0.f};

    for (int k0 = 0; k0 < 512; k0 += 64) {
        __syncthreads();
#pragma unroll
        for (int d = 0; d < 4; ++d)
            dma16(xb + (size_t)(m0 + d * 32 + srow) * 512 + k0 + schunk * 8,
                  (char*)As + d * 4096 + woff);
#pragma unroll
        for (int d = 0; d < 2; ++d)
            dma16(wT + (size_t)(n0 + d * 32 + srow) * 512 + k0 + schunk * 8,
                  (char*)Bs + d * 4096 + woff);
        __syncthreads();
#pragma unroll
        for (int kh = 0; kh < 2; ++kh) {
            const int ch = (kh * 4 + quad) ^ rchunk;
            bf16x8 af[4], bf[2];
#pragma unroll
            for (int mt = 0; mt < 4; ++mt)
                af[mt] = *(const bf16x8*)(As + (wm * 64 + mt * 16 + n16) * 64 + ch * 8);
#pragma unroll
            for (int nt = 0; nt < 2; ++nt)
                bf[nt] = *(const bf16x8*)(Bs + (wn * 32 + nt * 16 + n16) * 64 + ch * 8);
            if (!isv) {
#pragma unroll
                for (int mt = 0; mt < 4; ++mt)
#pragma unroll
                    for (int nt = 0; nt < 2; ++nt)
                        acc[mt][nt] = mfma16(af[mt], bf[nt], acc[mt][nt]);
            } else {
#pragma unroll
                for (int mt = 0; mt < 4; ++mt)
#pragma unroll
                    for (int nt = 0; nt < 2; ++nt)
                        acc[mt][nt] = mfma16(bf[nt], af[mt], acc[mt][nt]);
            }
        }
    }

    if (!isv) {
        // q/k scatter: row = i (quad*4+r), col = n-col (n16, d-contiguous)
#pragma unroll
        for (int mt = 0; mt < 4; ++mt)
#pragma unroll
            for (int nt = 0; nt < 2; ++nt)
#pragma unroll
                for (int r = 0; r < 4; ++r) {
                    int m = m0 + wm * 64 + mt * 16 + quad * 4 + r;
                    int n = n0 + wn * 32 + nt * 16 + n16;
                    int b = m >> 11, i = m & 2047;
                    int sg = n >> 9, cc = n & 511;
                    int h = cc >> 6, d = cc & 63;
                    size_t bh = (size_t)(b * NH + h);
                    float fv = acc[mt][nt][r];
                    if (sg == 0) q[(bh * NN + i) * HD + d] = (__bf16)(fv * SCALE);
                    else         kk[(bh * NN + i) * HD + d] = (__bf16)fv;
                }
    } else {
        // v transposed tile: row = w-col d (quad*4+r), col = i (n16, contiguous)
#pragma unroll
        for (int mt = 0; mt < 4; ++mt)
#pragma unroll
            for (int nt = 0; nt < 2; ++nt)
#pragma unroll
                for (int r = 0; r < 4; ++r) {
                    int m = m0 + wm * 64 + mt * 16 + n16;              // x row
                    int n = n0 + wn * 32 + nt * 16 + quad * 4 + r;     // w col
                    int b = m >> 11, i = m & 2047;
                    int cc = n & 511;
                    int h = cc >> 6, d = cc & 63;
                    size_t bh = (size_t)(b * NH + h);
                    vT[(bh * HD + d) * NN + i] = (__bf16)acc[mt][nt][r];
                }
    }
}

// ---------------------------------------------------------------------------
// Kernel 3: flash attention, 32x32 MFMA, split-j x4, poly-exp. (R10, proven)
// ---------------------------------------------------------------------------
__global__ __launch_bounds__(256, 4) void flash_attn(const __bf16* __restrict__ qb,
                                                     const __bf16* __restrict__ kb,
                                                     const __bf16* __restrict__ vTb,
                                                     const __bf16* __restrict__ maskb,
                                                     __bf16* __restrict__ Opart,
                                                     float* __restrict__ lpart) {
    __shared__ __bf16 Ks[64 * 64];    // 8 KB, rows j-local, XOR swizzle
    __shared__ __bf16 Vs[64 * 64];    // 8 KB, rows d, XOR swizzle
    __shared__ __bf16 Ms[128 * 64];   // 16 KB, rows i-local, XOR swizzle

    const int t = threadIdx.x;
    const int lane = t & 63;
    const int w = t >> 6;
    const int l32 = lane & 31;
    const int half = lane >> 5;

    const int blk = blockIdx.x;
    const int split = blk & 3;
    const int it = (blk >> 2) & 15;
    const int h = (blk >> 6) & 7;
    const int b = blk >> 9;
    const int i0 = it * 128;
    const int bh = b * NH + h;
    const int il = w * 32 + l32;
    const int iw = i0 + il;

    bf16x8 qf[4];
    {
        const __bf16* qrow = qb + ((size_t)bh * NN + iw) * HD;
#pragma unroll
        for (int kc = 0; kc < 4; ++kc)
            qf[kc] = *(const bf16x8*)(qrow + kc * 16 + half * 8);
    }

    floatx16 O0 = {}, O1 = {};
    float lp = 0.f;

    const int drow = t >> 3;
    const int dchunk = (t & 7) ^ ((t >> 3) & 7);
    const int woff = w * 1024;
    const int rs = l32 & 7;

    const __bf16* kg = kb + (size_t)bh * NN * HD;
    const __bf16* vg = vTb + (size_t)bh * HD * NN;
    const __bf16* mg = maskb + ((size_t)b * NN + i0) * NN;

    int j0 = split * (NN / 4);
    for (int iter = 0; iter < (NN / 4) / 64; ++iter, j0 += 64) {
        __syncthreads();
#pragma unroll
        for (int d = 0; d < 2; ++d) {
            dma16(kg + (size_t)(j0 + d * 32 + drow) * HD + dchunk * 8,
                  (char*)Ks + d * 4096 + woff);
            dma16(vg + (size_t)(d * 32 + drow) * NN + j0 + dchunk * 8,
                  (char*)Vs + d * 4096 + woff);
        }
#pragma unroll
        for (int d = 0; d < 4; ++d)
            dma16(mg + (size_t)(d * 32 + drow) * NN + j0 + dchunk * 8,
                  (char*)Ms + d * 4096 + woff);
        __syncthreads();

        floatx16 S0 = {}, S1 = {};
#pragma unroll
        for (int kc = 0; kc < 4; ++kc) {
            const int cs = ((kc * 2 + half) ^ rs) * 8;
            S0 = mfma32(*(const bf16x8*)(Ks + l32 * 64 + cs), qf[kc], S0);
            S1 = mfma32(*(const bf16x8*)(Ks + (32 + l32) * 64 + cs), qf[kc], S1);
        }

        pk_u64 pk[8];
#pragma unroll
        for (int G = 0; G < 8; ++G) {
            bf16x4 mv = *(const bf16x4*)(Ms + il * 64 + ((G ^ rs) * 8) + half * 4);
#pragma unroll
            for (int rr = 0; rr < 4; ++rr) {
                float s = (G < 4) ? S0[(G & 3) * 4 + rr] : S1[(G & 3) * 4 + rr];
                float x = s * (float)mv[rr];
                float p = fmaf(x, fmaf(0.5f, x, 1.0f), 1.0f);
                lp += p;
                pk[G].v[rr] = (__bf16)p;
            }
        }

#pragma unroll
        for (int kc = 0; kc < 4; ++kc) {
            u64 pa = pk[2 * kc].u, pb = pk[2 * kc + 1].u;
            u64 send = half ? pa : pb;
            u64 recv = __shfl_xor(send, 32);
            frag_u64 af;
            af.u[0] = half ? recv : pa;
            af.u[1] = half ? pb : recv;
            const int cs = ((kc * 2 + half) ^ rs) * 8;
            O0 = mfma32(af.v, *(const bf16x8*)(Vs + l32 * 64 + cs), O0);
            O1 = mfma32(af.v, *(const bf16x8*)(Vs + (32 + l32) * 64 + cs), O1);
        }
    }

    lp += __shfl_xor(lp, 32);
    const size_t sb = (size_t)(split * BB * NH + bh);
    if (half == 0)
        lpart[sb * NN + iw] = lp;
#pragma unroll
    for (int reg = 0; reg < 16; ++reg) {
        int i = i0 + w * 32 + (reg & 3) + 8 * (reg >> 2) + 4 * half;
        Opart[(sb * NN + i) * HD + l32] = (__bf16)O0[reg];
        Opart[(sb * NN + i) * HD + 32 + l32] = (__bf16)O1[reg];
    }
}

// ---------------------------------------------------------------------------
// Kernel 4: combine 4 splits -> ohb [b, n, h*d] bf16
// ---------------------------------------------------------------------------
__global__ __launch_bounds__(256) void combine(const __bf16* __restrict__ Opart,
                                               const float* __restrict__ lpart,
                                               __bf16* __restrict__ ohb) {
    int g = blockIdx.x * 256 + threadIdx.x;
    int d0 = (g & 7) * 8;
    int n = (g >> 3) & 2047;
    int bh = g >> 14;
    int b = bh >> 3, h = bh & 7;
    float o[8] = {};
    float l = 0.f;
#pragma unroll
    for (int s = 0; s < 4; ++s) {
        size_t sb = (size_t)(s * BB * NH + bh);
        bf16x8 ov = *(const bf16x8*)(Opart + (sb * NN + n) * HD + d0);
#pragma unroll
        for (int e = 0; e < 8; ++e) o[e] += (float)ov[e];
        l += lpart[sb * NN + n];
    }
    float inv = 1.0f / l;
    bf16x8 r;
#pragma unroll
    for (int e = 0; e < 8; ++e) r[e] = (__bf16)(o[e] * inv);
    *(bf16x8*)(ohb + ((size_t)b * NN + n) * (NH * HD) + h * HD + d0) = r;
}

// ---------------------------------------------------------------------------
// Kernel 5: out = ohb @ w_out + b_out via MFMA + DMA staging.
// ---------------------------------------------------------------------------
__global__ __launch_bounds__(256) void out_mfma(const __bf16* __restrict__ A,
                                                const __bf16* __restrict__ wT,
                                                const float* __restrict__ bias,
                                                float* __restrict__ out) {
    __shared__ __bf16 As[64 * 64];    // 8 KB
    __shared__ __bf16 Bs[64 * 64];    // 8 KB
    const int t = threadIdx.x;
    const int lane = t & 63, w = t >> 6;
    const int n16 = lane & 15, quad = lane >> 4;
    const int wm = w >> 1, wn = w & 1;
    const int m0 = blockIdx.y * 64, n0 = blockIdx.x * 64;

    const int srow = t >> 3;
    const int schunk = (t & 7) ^ ((t >> 3) & 7);
    const int woff = w * 1024;
    const int rchunk = (n16 & 7);

    floatx4 acc[2][2];
#pragma unroll
    for (int mt = 0; mt < 2; ++mt)
#pragma unroll
        for (int nt = 0; nt < 2; ++nt) acc[mt][nt] = (floatx4){0.f, 0.f, 0.f, 0.f};

    for (int k0 = 0; k0 < 512; k0 += 64) {
        __syncthreads();
#pragma unroll
        for (int d = 0; d < 2; ++d) {
            dma16(A + (size_t)(m0 + d * 32 + srow) * 512 + k0 + schunk * 8,
                  (char*)As + d * 4096 + woff);
            dma16(wT + (size_t)(n0 + d * 32 + srow) * 512 + k0 + schunk * 8,
                  (char*)Bs + d * 4096 + woff);
        }
        __syncthreads();
#pragma unroll
        for (int kh = 0; kh < 2; ++kh) {
            const int ch = (kh * 4 + quad) ^ rchunk;
            bf16x8 af[2], bf[2];
#pragma unroll
            for (int mt = 0; mt < 2; ++mt)
                af[mt] = *(const bf16x8*)(As + (wm * 32 + mt * 16 + n16) * 64 + ch * 8);
#pragma unroll
            for (int nt = 0; nt < 2; ++nt)
                bf[nt] = *(const bf16x8*)(Bs + (wn * 32 + nt * 16 + n16) * 64 + ch * 8);
#pragma unroll
            for (int mt = 0; mt < 2; ++mt)
#pragma unroll
                for (int nt = 0; nt < 2; ++nt)
                    acc[mt][nt] = mfma16(af[mt], bf[nt], acc[mt][nt]);
        }
    }

#pragma unroll
    for (int mt = 0; mt < 2; ++mt)
#pragma unroll
        for (int nt = 0; nt < 2; ++nt)
#pragma unroll
            for (int r = 0; r < 4; ++r) {
                int m = m0 + wm * 32 + mt * 16 + quad * 4 + r;
                int n = n0 + wn * 32 + nt * 16 + n16;
                out[(size_t)m * 512 + n] = acc[mt][nt][r] + bias[n];
            }
}

extern "C" void kernel_launch(void* const* d_in, const int* in_sizes, int n_in,
                              void* d_out, int out_size, void* d_ws, size_t ws_size,
                              hipStream_t stream) {
    const float* x     = (const float*)d_in[0];
    const float* adj   = (const float*)d_in[1];
    const float* w_qkv = (const float*)d_in[2];
    const float* w_out = (const float*)d_in[3];
    const float* b_out = (const float*)d_in[4];
    float* out = (float*)d_out;
    char* wsb = (char*)d_ws;

    // workspace byte layout (46.5 MiB)
    __bf16* wqkvT = (__bf16*)(wsb + 0);                  // 1.5 MiB
    __bf16* woutT = (__bf16*)(wsb + (3u << 19));         // 0.5 MiB
    __bf16* q     = (__bf16*)(wsb + (2u << 20));         // 4 MiB
    __bf16* ohb   = (__bf16*)(wsb + (2u << 20));         // aliases q (q dead at combine)
    __bf16* k     = (__bf16*)(wsb + (6u << 20));         // 4 MiB
    __bf16* vT    = (__bf16*)(wsb + (10u << 20));        // 4 MiB
    __bf16* mask  = (__bf16*)(wsb + (14u << 20));        // 16 MiB
    __bf16* Opart = (__bf16*)(wsb + (30u << 20));        // 16 MiB (4 splits)
    __bf16* xb    = (__bf16*)(wsb + (30u << 20));        // aliases Opart (dead after qkv)
    float*  lpart = (float*) (wsb + (46u << 20));        // 512 KiB

    prep<<<6144, 256, 0, stream>>>(adj, mask, x, xb, w_qkv, wqkvT, w_out, woutT);
    qkv_mfma<<<dim3(1536 / 64, 4096 / 128), 256, 0, stream>>>(xb, wqkvT, q, k, vT);
    flash_attn<<<BB * NH * 16 * 4, 256, 0, stream>>>(q, k, vT, mask, Opart, lpart);
    combine<<<1024, 256, 0, stream>>>(Opart, lpart, ohb);
    out_mfma<<<dim3(512 / 64, 4096 / 64), 256, 0, stream>>>(ohb, woutT, b_out, out);
}